// Round 2
// baseline (558.711 us; speedup 1.0000x reference)
//
#include <hip/hip_runtime.h>
#include <cmath>

#define Hdim 512
#define Udim 32
#define Bdim 32
#define Tdim 2048
#define RM   128   // rows per block in K1
#define KC   32    // k-chunk
#define LDX  36    // padded LDS row stride (floats): row stride ≡ 4 banks -> conflict-free b128
#define NW   16    // waves per block in K2

// ---------------- Kernel 1: gamma/beta GEMMs + tanh + lambd combine -> delta [B*T, U] ----------
// LDS staging for both acts and weights (round-0 structure), but 4-row x 4-u register blocking:
// per q-iter: 16 ds_read_b128 feed 128 FMAs (8:1, was 5.3:1). All LDS reads are 8-lane
// broadcasts across disjoint banks (act row stride 36 ≡ +4 banks, weight u-slices 4-word).
__global__ __launch_bounds__(256, 3) void k1_gemm_act(
    const float* __restrict__ x, const float* __restrict__ tin,
    const float* __restrict__ kx, const float* __restrict__ kt,
    const float* __restrict__ bx, const float* __restrict__ bt,
    const float* __restrict__ lambd, float* __restrict__ delta)
{
    __shared__ float xs[RM * LDX];    // 18432 B
    __shared__ float ts[RM * LDX];    // 18432 B
    __shared__ float kxs[KC * Udim];  // 4096 B
    __shared__ float kts[KC * Udim];  // 4096 B   (total 45056 B -> 3 blocks/CU)

    const int tid   = threadIdx.x;
    const int u0    = (tid & 7) * 4;   // 8 u-groups of 4
    const int r_thr = tid >> 3;        // 0..31 ; rows r_thr + 32*j, j in 0..3
    const int row0  = blockIdx.x * RM;
    const int sf4   = tid & 7;
    const int srow  = tid >> 3;

    const float4* xg  = (const float4*)x;
    const float4* tg  = (const float4*)tin;
    const float4* kxg = (const float4*)kx;
    const float4* ktg = (const float4*)kt;

    float4 px[4], pt[4], pwx, pwt;
    float accx[4][4], acct[4][4];
#pragma unroll
    for (int j = 0; j < 4; ++j)
#pragma unroll
        for (int uu = 0; uu < 4; ++uu) { accx[j][uu] = 0.f; acct[j][uu] = 0.f; }

    // prefetch chunk 0
#pragma unroll
    for (int l = 0; l < 4; ++l) {
        const size_t row = (size_t)(row0 + srow + 32 * l);
        px[l] = xg[row * (Hdim / 4) + sf4];
        pt[l] = tg[row * (Hdim / 4) + sf4];
    }
    pwx = kxg[tid];   // chunk c weights: 256 float4 at f4-index c*256
    pwt = ktg[tid];

#pragma unroll 1
    for (int c = 0; c < Hdim / KC; ++c) {
        __syncthreads();
#pragma unroll
        for (int l = 0; l < 4; ++l) {
            *(float4*)&xs[(srow + 32 * l) * LDX + sf4 * 4] = px[l];
            *(float4*)&ts[(srow + 32 * l) * LDX + sf4 * 4] = pt[l];
        }
        *(float4*)&kxs[tid * 4] = pwx;
        *(float4*)&kts[tid * 4] = pwt;
        __syncthreads();

        if (c + 1 < Hdim / KC) {
            const int cn = c + 1;
#pragma unroll
            for (int l = 0; l < 4; ++l) {
                const size_t row = (size_t)(row0 + srow + 32 * l);
                px[l] = xg[row * (Hdim / 4) + cn * (KC / 4) + sf4];
                pt[l] = tg[row * (Hdim / 4) + cn * (KC / 4) + sf4];
            }
            pwx = kxg[cn * (KC * Udim / 4) + tid];
            pwt = ktg[cn * (KC * Udim / 4) + tid];
        }

#pragma unroll
        for (int q = 0; q < KC / 4; ++q) {
            const int k0 = q * 4;
            float wx[4][4], wt[4][4];
#pragma unroll
            for (int kk = 0; kk < 4; ++kk) {
                float4 vx = *(const float4*)&kxs[(k0 + kk) * Udim + u0];
                wx[kk][0] = vx.x; wx[kk][1] = vx.y; wx[kk][2] = vx.z; wx[kk][3] = vx.w;
                float4 vt = *(const float4*)&kts[(k0 + kk) * Udim + u0];
                wt[kk][0] = vt.x; wt[kk][1] = vt.y; wt[kk][2] = vt.z; wt[kk][3] = vt.w;
            }
            float ax[4][4], at_[4][4];
#pragma unroll
            for (int j = 0; j < 4; ++j) {
                float4 va = *(const float4*)&xs[(r_thr + 32 * j) * LDX + k0];
                ax[j][0] = va.x; ax[j][1] = va.y; ax[j][2] = va.z; ax[j][3] = va.w;
                float4 vb = *(const float4*)&ts[(r_thr + 32 * j) * LDX + k0];
                at_[j][0] = vb.x; at_[j][1] = vb.y; at_[j][2] = vb.z; at_[j][3] = vb.w;
            }
#pragma unroll
            for (int j = 0; j < 4; ++j)
#pragma unroll
                for (int kk = 0; kk < 4; ++kk)
#pragma unroll
                    for (int uu = 0; uu < 4; ++uu) {
                        accx[j][uu] = fmaf(ax[j][kk], wx[kk][uu], accx[j][uu]);
                        acct[j][uu] = fmaf(at_[j][kk], wt[kk][uu], acct[j][uu]);
                    }
        }
    }

    // epilogue
    float4 bxv = *(const float4*)&bx[u0];
    float4 btv = *(const float4*)&bt[u0];
    float bxa[4] = { bxv.x, bxv.y, bxv.z, bxv.w };
    float bta[4] = { btv.x, btv.y, btv.z, btv.w };

#pragma unroll
    for (int j = 0; j < 4; ++j) {
        const int grow = row0 + r_thr + 32 * j;
        const float lam = lambd[grow & (Tdim - 1)];
        float o[4];
#pragma unroll
        for (int uu = 0; uu < 4; ++uu) {
            float g  = tanhf(accx[j][uu] + bxa[uu]);
            float be = tanhf(acct[j][uu] + bta[uu]);
            o[uu] = lam * g + (1.0f - lam) * be;
        }
        *(float4*)&delta[(size_t)grow * Udim + u0] = make_float4(o[0], o[1], o[2], o[3]);
    }
}

// ---------------- Kernel 2: scores = delta @ kernel_a, softmax over T -> alpha -----------------
// No LDS delta staging. Each wave walks rows r = ty + 16*i; the row address is wave-uniform
// (readfirstlane) -> compiler can emit s_load through K$ (row data lands in SGPRs, one SGPR
// operand per FMA). 16 waves share the 256 KB delta slice through K$/L2 (same-b blocks on
// same XCD). Software prefetch of row i+1 hides the load latency behind 32 FMAs.
__global__ __launch_bounds__(1024, 4) void k2_softmax(
    const float* __restrict__ delta, const float* __restrict__ ka_g,
    float* __restrict__ alpha)
{
    __shared__ float ms[NW][64];
    __shared__ float ls[NW][64];

    const int tid = threadIdx.x;
    const int tx  = tid & 63;
    const int ty  = __builtin_amdgcn_readfirstlane(tid >> 6);  // wave-uniform wave id 0..15
    const int b   = blockIdx.x & 31;
    const int ht  = blockIdx.x >> 5;   // 0..7
    const int h   = ht * 64 + tx;

    // kernel_a column for this lane's h (32 VGPRs)
    float ka[Udim];
#pragma unroll
    for (int u = 0; u < Udim; ++u) ka[u] = ka_g[u * Hdim + h];

    const float* dbase = delta + (size_t)b * Tdim * Udim;

    // ---- pass 1: online (m, l); rows r = ty + 16*i ----
    float m = -1e30f, l = 0.f;
    {
        float4 q[8];
        {
            const float4* p = (const float4*)(dbase + (size_t)ty * Udim);
#pragma unroll
            for (int j = 0; j < 8; ++j) q[j] = p[j];
        }
#pragma unroll 2
        for (int i = 0; i < Tdim / NW; ++i) {
            // prefetch next row (last iter reloads row ty; harmless)
            const int rn = ty + 16 * ((i + 1) & (Tdim / NW - 1));
            const float4* np = (const float4*)(dbase + (size_t)rn * Udim);
            float4 nq[8];
#pragma unroll
            for (int j = 0; j < 8; ++j) nq[j] = np[j];

            float s0 = 0.f, s1 = 0.f, s2 = 0.f, s3 = 0.f;
#pragma unroll
            for (int j = 0; j < 8; ++j) {
                s0 = fmaf(q[j].x, ka[4 * j],     s0);
                s1 = fmaf(q[j].y, ka[4 * j + 1], s1);
                s2 = fmaf(q[j].z, ka[4 * j + 2], s2);
                s3 = fmaf(q[j].w, ka[4 * j + 3], s3);
            }
            const float s = (s0 + s1) + (s2 + s3);
            const float mn = fmaxf(m, s);
            l = l * __expf(m - mn) + __expf(s - mn);
            m = mn;
#pragma unroll
            for (int j = 0; j < 8; ++j) q[j] = nq[j];
        }
    }

    ms[ty][tx] = m;
    ls[ty][tx] = l;
    __syncthreads();
    float M = -1e30f;
#pragma unroll
    for (int w = 0; w < NW; ++w) M = fmaxf(M, ms[w][tx]);
    float L = 0.f;
#pragma unroll
    for (int w = 0; w < NW; ++w) L += ls[w][tx] * __expf(ms[w][tx] - M);
    const float rinv = 1.0f / L;

    // ---- pass 2: recompute scores, write alpha ----
    float* abase = alpha + (size_t)b * Tdim * Hdim + h;
    {
        float4 q[8];
        {
            const float4* p = (const float4*)(dbase + (size_t)ty * Udim);
#pragma unroll
            for (int j = 0; j < 8; ++j) q[j] = p[j];
        }
#pragma unroll 2
        for (int i = 0; i < Tdim / NW; ++i) {
            const int rn = ty + 16 * ((i + 1) & (Tdim / NW - 1));
            const float4* np = (const float4*)(dbase + (size_t)rn * Udim);
            float4 nq[8];
#pragma unroll
            for (int j = 0; j < 8; ++j) nq[j] = np[j];

            float s0 = 0.f, s1 = 0.f, s2 = 0.f, s3 = 0.f;
#pragma unroll
            for (int j = 0; j < 8; ++j) {
                s0 = fmaf(q[j].x, ka[4 * j],     s0);
                s1 = fmaf(q[j].y, ka[4 * j + 1], s1);
                s2 = fmaf(q[j].z, ka[4 * j + 2], s2);
                s3 = fmaf(q[j].w, ka[4 * j + 3], s3);
            }
            const float s = (s0 + s1) + (s2 + s3);
            const int t = ty + 16 * i;
            abase[(size_t)t * Hdim] = __expf(s - M) * rinv;
#pragma unroll
            for (int j = 0; j < 8; ++j) q[j] = nq[j];
        }
    }
}

extern "C" void kernel_launch(void* const* d_in, const int* in_sizes, int n_in,
                              void* d_out, int out_size, void* d_ws, size_t ws_size,
                              hipStream_t stream) {
    const float* x     = (const float*)d_in[0];
    const float* tin   = (const float*)d_in[1];
    const float* kx    = (const float*)d_in[2];
    const float* kt    = (const float*)d_in[3];
    const float* ka    = (const float*)d_in[4];
    const float* bx    = (const float*)d_in[5];
    const float* bt    = (const float*)d_in[6];
    const float* lambd = (const float*)d_in[7];
    float* alpha = (float*)d_out;
    float* delta = (float*)d_ws;   // B*T*U*4 = 8 MB

    k1_gemm_act<<<(Bdim * Tdim) / RM, 256, 0, stream>>>(x, tin, kx, kt, bx, bt, lambd, delta);
    k2_softmax<<<256, 1024, 0, stream>>>(delta, ka, alpha);
}

// Round 3
// 554.704 us; speedup vs baseline: 1.0072x; 1.0072x over previous
//
#include <hip/hip_runtime.h>
#include <cmath>

#define Hdim 512
#define Udim 32
#define Bdim 32
#define Tdim 2048
#define RM   32    // rows per block in K1 (small blocks -> 8 independent barrier groups/CU)
#define KC   32    // k-chunk
#define LDX  36    // padded LDS row stride (floats): conflict-free b128 (measured 0 conflicts)
#define NW   16    // waves per block in K2

// ---------------- Kernel 1: gamma/beta GEMMs + tanh + lambd combine -> delta [B*T, U] ----------
// Round-0 inner shape (j=2 rows x 4 u per thread; 12 ds_read_b128 / 64 FMA, zero bank conflicts)
// but RM=32 / 128-thread blocks: grid 2048 -> 8 blocks/CU (LDS 17.4 KB allows 9). Wall was shown
// to scale with 1/concurrency (r0: 4 blk=150us, r2: 2 blk=251us) -> 8 independent barrier domains
// overlap the per-chunk load-drain that a convoyed block exposes.
__global__ __launch_bounds__(128, 4) void k1_gemm_act(
    const float* __restrict__ x, const float* __restrict__ tin,
    const float* __restrict__ kx, const float* __restrict__ kt,
    const float* __restrict__ bx, const float* __restrict__ bt,
    const float* __restrict__ lambd, float* __restrict__ delta)
{
    __shared__ float xs[RM * LDX];    // 4608 B
    __shared__ float ts[RM * LDX];    // 4608 B
    __shared__ float kxs[KC * Udim];  // 4096 B
    __shared__ float kts[KC * Udim];  // 4096 B  (17408 B total)

    const int tid   = threadIdx.x;     // 0..127
    const int u0    = (tid & 7) * 4;   // 8 u-groups of 4
    const int r_thr = tid >> 3;        // 0..15 ; rows r_thr + 16*j, j in {0,1}
    const int row0  = blockIdx.x * RM;
    const int sf4   = tid & 7;
    const int srow  = tid >> 3;        // 0..15

    const float4* xg  = (const float4*)x;
    const float4* tg  = (const float4*)tin;
    const float4* kxg = (const float4*)kx;
    const float4* ktg = (const float4*)kt;

    float4 px[2], pt[2], pwx[2], pwt[2];
    float accx[2][4], acct[2][4];
#pragma unroll
    for (int j = 0; j < 2; ++j)
#pragma unroll
        for (int uu = 0; uu < 4; ++uu) { accx[j][uu] = 0.f; acct[j][uu] = 0.f; }

    // prefetch chunk 0
#pragma unroll
    for (int l = 0; l < 2; ++l) {
        const size_t row = (size_t)(row0 + srow + 16 * l);
        px[l] = xg[row * (Hdim / 4) + sf4];
        pt[l] = tg[row * (Hdim / 4) + sf4];
    }
    pwx[0] = kxg[tid];       pwx[1] = kxg[128 + tid];   // chunk weights: 256 f4 per matrix
    pwt[0] = ktg[tid];       pwt[1] = ktg[128 + tid];

#pragma unroll 1
    for (int c = 0; c < Hdim / KC; ++c) {
        __syncthreads();
#pragma unroll
        for (int l = 0; l < 2; ++l) {
            *(float4*)&xs[(srow + 16 * l) * LDX + sf4 * 4] = px[l];
            *(float4*)&ts[(srow + 16 * l) * LDX + sf4 * 4] = pt[l];
        }
        *(float4*)&kxs[tid * 4]         = pwx[0];
        *(float4*)&kxs[(tid + 128) * 4] = pwx[1];
        *(float4*)&kts[tid * 4]         = pwt[0];
        *(float4*)&kts[(tid + 128) * 4] = pwt[1];
        __syncthreads();

        if (c + 1 < Hdim / KC) {
            const int cn = c + 1;
#pragma unroll
            for (int l = 0; l < 2; ++l) {
                const size_t row = (size_t)(row0 + srow + 16 * l);
                px[l] = xg[row * (Hdim / 4) + cn * (KC / 4) + sf4];
                pt[l] = tg[row * (Hdim / 4) + cn * (KC / 4) + sf4];
            }
            pwx[0] = kxg[cn * 256 + tid];  pwx[1] = kxg[cn * 256 + 128 + tid];
            pwt[0] = ktg[cn * 256 + tid];  pwt[1] = ktg[cn * 256 + 128 + tid];
        }

#pragma unroll
        for (int q = 0; q < KC / 4; ++q) {
            const int k0 = q * 4;
            float wx[4][4], wt[4][4], ax[2][4], at_[2][4];
#pragma unroll
            for (int kk = 0; kk < 4; ++kk) {
                float4 vx = *(const float4*)&kxs[(k0 + kk) * Udim + u0];
                wx[kk][0] = vx.x; wx[kk][1] = vx.y; wx[kk][2] = vx.z; wx[kk][3] = vx.w;
                float4 vt = *(const float4*)&kts[(k0 + kk) * Udim + u0];
                wt[kk][0] = vt.x; wt[kk][1] = vt.y; wt[kk][2] = vt.z; wt[kk][3] = vt.w;
            }
#pragma unroll
            for (int j = 0; j < 2; ++j) {
                float4 va = *(const float4*)&xs[(r_thr + 16 * j) * LDX + k0];
                ax[j][0] = va.x; ax[j][1] = va.y; ax[j][2] = va.z; ax[j][3] = va.w;
                float4 vb = *(const float4*)&ts[(r_thr + 16 * j) * LDX + k0];
                at_[j][0] = vb.x; at_[j][1] = vb.y; at_[j][2] = vb.z; at_[j][3] = vb.w;
            }
#pragma unroll
            for (int j = 0; j < 2; ++j)
#pragma unroll
                for (int kk = 0; kk < 4; ++kk)
#pragma unroll
                    for (int uu = 0; uu < 4; ++uu) {
                        accx[j][uu] = fmaf(ax[j][kk], wx[kk][uu], accx[j][uu]);
                        acct[j][uu] = fmaf(at_[j][kk], wt[kk][uu], acct[j][uu]);
                    }
        }
    }

    // epilogue
    float4 bxv = *(const float4*)&bx[u0];
    float4 btv = *(const float4*)&bt[u0];
    float bxa[4] = { bxv.x, bxv.y, bxv.z, bxv.w };
    float bta[4] = { btv.x, btv.y, btv.z, btv.w };

#pragma unroll
    for (int j = 0; j < 2; ++j) {
        const int grow = row0 + r_thr + 16 * j;
        const float lam = lambd[grow & (Tdim - 1)];
        float o[4];
#pragma unroll
        for (int uu = 0; uu < 4; ++uu) {
            float g  = tanhf(accx[j][uu] + bxa[uu]);
            float be = tanhf(acct[j][uu] + bta[uu]);
            o[uu] = lam * g + (1.0f - lam) * be;
        }
        *(float4*)&delta[(size_t)grow * Udim + u0] = make_float4(o[0], o[1], o[2], o[3]);
    }
}

// ---------------- Kernel 2: scores = delta @ kernel_a, softmax over T -> alpha -----------------
// (unchanged from round 2 to isolate the k1 delta)
__global__ __launch_bounds__(1024, 4) void k2_softmax(
    const float* __restrict__ delta, const float* __restrict__ ka_g,
    float* __restrict__ alpha)
{
    __shared__ float ms[NW][64];
    __shared__ float ls[NW][64];

    const int tid = threadIdx.x;
    const int tx  = tid & 63;
    const int ty  = __builtin_amdgcn_readfirstlane(tid >> 6);  // wave-uniform wave id 0..15
    const int b   = blockIdx.x & 31;
    const int ht  = blockIdx.x >> 5;   // 0..7
    const int h   = ht * 64 + tx;

    float ka[Udim];
#pragma unroll
    for (int u = 0; u < Udim; ++u) ka[u] = ka_g[u * Hdim + h];

    const float* dbase = delta + (size_t)b * Tdim * Udim;

    // ---- pass 1: online (m, l); rows r = ty + 16*i ----
    float m = -1e30f, l = 0.f;
    {
        float4 q[8];
        {
            const float4* p = (const float4*)(dbase + (size_t)ty * Udim);
#pragma unroll
            for (int j = 0; j < 8; ++j) q[j] = p[j];
        }
#pragma unroll 2
        for (int i = 0; i < Tdim / NW; ++i) {
            const int rn = ty + 16 * ((i + 1) & (Tdim / NW - 1));
            const float4* np = (const float4*)(dbase + (size_t)rn * Udim);
            float4 nq[8];
#pragma unroll
            for (int j = 0; j < 8; ++j) nq[j] = np[j];

            float s0 = 0.f, s1 = 0.f, s2 = 0.f, s3 = 0.f;
#pragma unroll
            for (int j = 0; j < 8; ++j) {
                s0 = fmaf(q[j].x, ka[4 * j],     s0);
                s1 = fmaf(q[j].y, ka[4 * j + 1], s1);
                s2 = fmaf(q[j].z, ka[4 * j + 2], s2);
                s3 = fmaf(q[j].w, ka[4 * j + 3], s3);
            }
            const float s = (s0 + s1) + (s2 + s3);
            const float mn = fmaxf(m, s);
            l = l * __expf(m - mn) + __expf(s - mn);
            m = mn;
#pragma unroll
            for (int j = 0; j < 8; ++j) q[j] = nq[j];
        }
    }

    ms[ty][tx] = m;
    ls[ty][tx] = l;
    __syncthreads();
    float M = -1e30f;
#pragma unroll
    for (int w = 0; w < NW; ++w) M = fmaxf(M, ms[w][tx]);
    float L = 0.f;
#pragma unroll
    for (int w = 0; w < NW; ++w) L += ls[w][tx] * __expf(ms[w][tx] - M);
    const float rinv = 1.0f / L;

    // ---- pass 2: recompute scores, write alpha ----
    float* abase = alpha + (size_t)b * Tdim * Hdim + h;
    {
        float4 q[8];
        {
            const float4* p = (const float4*)(dbase + (size_t)ty * Udim);
#pragma unroll
            for (int j = 0; j < 8; ++j) q[j] = p[j];
        }
#pragma unroll 2
        for (int i = 0; i < Tdim / NW; ++i) {
            const int rn = ty + 16 * ((i + 1) & (Tdim / NW - 1));
            const float4* np = (const float4*)(dbase + (size_t)rn * Udim);
            float4 nq[8];
#pragma unroll
            for (int j = 0; j < 8; ++j) nq[j] = np[j];

            float s0 = 0.f, s1 = 0.f, s2 = 0.f, s3 = 0.f;
#pragma unroll
            for (int j = 0; j < 8; ++j) {
                s0 = fmaf(q[j].x, ka[4 * j],     s0);
                s1 = fmaf(q[j].y, ka[4 * j + 1], s1);
                s2 = fmaf(q[j].z, ka[4 * j + 2], s2);
                s3 = fmaf(q[j].w, ka[4 * j + 3], s3);
            }
            const float s = (s0 + s1) + (s2 + s3);
            const int t = ty + 16 * i;
            abase[(size_t)t * Hdim] = __expf(s - M) * rinv;
#pragma unroll
            for (int j = 0; j < 8; ++j) q[j] = nq[j];
        }
    }
}

extern "C" void kernel_launch(void* const* d_in, const int* in_sizes, int n_in,
                              void* d_out, int out_size, void* d_ws, size_t ws_size,
                              hipStream_t stream) {
    const float* x     = (const float*)d_in[0];
    const float* tin   = (const float*)d_in[1];
    const float* kx    = (const float*)d_in[2];
    const float* kt    = (const float*)d_in[3];
    const float* ka    = (const float*)d_in[4];
    const float* bx    = (const float*)d_in[5];
    const float* bt    = (const float*)d_in[6];
    const float* lambd = (const float*)d_in[7];
    float* alpha = (float*)d_out;
    float* delta = (float*)d_ws;   // B*T*U*4 = 8 MB

    k1_gemm_act<<<(Bdim * Tdim) / RM, 128, 0, stream>>>(x, tin, kx, kt, bx, bt, lambd, delta);
    k2_softmax<<<256, 1024, 0, stream>>>(delta, ka, alpha);
}

// Round 4
// 515.485 us; speedup vs baseline: 1.0839x; 1.0761x over previous
//
#include <hip/hip_runtime.h>
#include <cmath>

#define Hdim 512
#define Udim 32
#define Bdim 32
#define Tdim 2048
#define RM   64    // rows per block in K1
#define KC   32    // k-chunk
#define LDX  36    // padded LDS row stride (floats) - measured 0 bank conflicts
#define CH   128   // delta rows per LDS chunk in K2

// ---------------- Kernel 1: gamma/beta GEMMs + tanh + lambd combine -> delta [B*T, U] ----------
// Round-0 proven shape (RM=64, 256 thr, j=2 x u=4, 12 ds_read_b128 / 64 FMA) with DOUBLE-BUFFERED
// LDS: one barrier per chunk (was 2), ds_writes + global prefetch issued BEFORE compute so staging
// overlaps the previous chunk's FMAs. LDS 52 KB -> 3 blocks/CU (matches measured occupancy).
__global__ __launch_bounds__(256, 3) void k1_gemm_act(
    const float* __restrict__ x, const float* __restrict__ tin,
    const float* __restrict__ kx, const float* __restrict__ kt,
    const float* __restrict__ bx, const float* __restrict__ bt,
    const float* __restrict__ lambd, float* __restrict__ delta)
{
    __shared__ float xs[2][RM * LDX];    // 2 x 9216 B
    __shared__ float ts[2][RM * LDX];    // 2 x 9216 B
    __shared__ float kxs[2][KC * Udim];  // 2 x 4096 B
    __shared__ float kts[2][KC * Udim];  // 2 x 4096 B  (53248 B total)

    const int tid   = threadIdx.x;
    const int u0    = (tid & 7) * 4;
    const int r_thr = tid >> 3;       // 0..31 ; rows r_thr + 32*j, j in {0,1}
    const int row0  = blockIdx.x * RM;
    const int lk4   = tid & 7;
    const int lrow  = tid >> 3;

    const float4* xg  = (const float4*)x;
    const float4* tg  = (const float4*)tin;
    const float4* kxg = (const float4*)kx;
    const float4* ktg = (const float4*)kt;

    float4 px[2], pt[2], pwx, pwt;
    float accx[2][4], acct[2][4];
#pragma unroll
    for (int j = 0; j < 2; ++j)
#pragma unroll
        for (int uu = 0; uu < 4; ++uu) { accx[j][uu] = 0.f; acct[j][uu] = 0.f; }

    // prefetch chunk 0 -> regs
#pragma unroll
    for (int l = 0; l < 2; ++l) {
        const size_t row = (size_t)(row0 + lrow + 32 * l);
        px[l] = xg[row * (Hdim / 4) + lk4];
        pt[l] = tg[row * (Hdim / 4) + lk4];
    }
    pwx = kxg[tid];
    pwt = ktg[tid];

    // stage chunk 0 -> buf 0
#pragma unroll
    for (int l = 0; l < 2; ++l) {
        *(float4*)&xs[0][(lrow + 32 * l) * LDX + lk4 * 4] = px[l];
        *(float4*)&ts[0][(lrow + 32 * l) * LDX + lk4 * 4] = pt[l];
    }
    *(float4*)&kxs[0][lrow * Udim + lk4 * 4] = pwx;
    *(float4*)&kts[0][lrow * Udim + lk4 * 4] = pwt;

    // prefetch chunk 1 -> regs
#pragma unroll
    for (int l = 0; l < 2; ++l) {
        const size_t row = (size_t)(row0 + lrow + 32 * l);
        px[l] = xg[row * (Hdim / 4) + (KC / 4) + lk4];
        pt[l] = tg[row * (Hdim / 4) + (KC / 4) + lk4];
    }
    pwx = kxg[256 + tid];
    pwt = ktg[256 + tid];

#pragma unroll 1
    for (int c = 0; c < Hdim / KC; ++c) {
        // One barrier per chunk: makes buf[c&1]'s writes (issued last iter, pre-compute)
        // visible, and guarantees buf[(c+1)&1]'s readers (iter c-1 compute) are done.
        __syncthreads();

        if (c + 1 < Hdim / KC) {
            const int nb = (c + 1) & 1;
#pragma unroll
            for (int l = 0; l < 2; ++l) {
                *(float4*)&xs[nb][(lrow + 32 * l) * LDX + lk4 * 4] = px[l];
                *(float4*)&ts[nb][(lrow + 32 * l) * LDX + lk4 * 4] = pt[l];
            }
            *(float4*)&kxs[nb][lrow * Udim + lk4 * 4] = pwx;
            *(float4*)&kts[nb][lrow * Udim + lk4 * 4] = pwt;

            if (c + 2 < Hdim / KC) {
                const int cn = c + 2;
#pragma unroll
                for (int l = 0; l < 2; ++l) {
                    const size_t row = (size_t)(row0 + lrow + 32 * l);
                    px[l] = xg[row * (Hdim / 4) + cn * (KC / 4) + lk4];
                    pt[l] = tg[row * (Hdim / 4) + cn * (KC / 4) + lk4];
                }
                pwx = kxg[cn * 256 + tid];
                pwt = ktg[cn * 256 + tid];
            }
        }

        const int cb = c & 1;
        const float* xsb = xs[cb];
        const float* tsb = ts[cb];
        const float* kxb = kxs[cb];
        const float* ktb = kts[cb];

#pragma unroll
        for (int q = 0; q < KC / 4; ++q) {
            const int k0 = q * 4;
            float wx[4][4], wt[4][4], ax[2][4], at_[2][4];
#pragma unroll
            for (int kk = 0; kk < 4; ++kk) {
                float4 vx = *(const float4*)&kxb[(k0 + kk) * Udim + u0];
                wx[kk][0] = vx.x; wx[kk][1] = vx.y; wx[kk][2] = vx.z; wx[kk][3] = vx.w;
                float4 vt = *(const float4*)&ktb[(k0 + kk) * Udim + u0];
                wt[kk][0] = vt.x; wt[kk][1] = vt.y; wt[kk][2] = vt.z; wt[kk][3] = vt.w;
            }
#pragma unroll
            for (int j = 0; j < 2; ++j) {
                float4 va = *(const float4*)&xsb[(r_thr + 32 * j) * LDX + k0];
                ax[j][0] = va.x; ax[j][1] = va.y; ax[j][2] = va.z; ax[j][3] = va.w;
                float4 vb = *(const float4*)&tsb[(r_thr + 32 * j) * LDX + k0];
                at_[j][0] = vb.x; at_[j][1] = vb.y; at_[j][2] = vb.z; at_[j][3] = vb.w;
            }
#pragma unroll
            for (int j = 0; j < 2; ++j)
#pragma unroll
                for (int kk = 0; kk < 4; ++kk)
#pragma unroll
                    for (int uu = 0; uu < 4; ++uu) {
                        accx[j][uu] = fmaf(ax[j][kk], wx[kk][uu], accx[j][uu]);
                        acct[j][uu] = fmaf(at_[j][kk], wt[kk][uu], acct[j][uu]);
                    }
        }
    }

    // epilogue
    float4 bxv = *(const float4*)&bx[u0];
    float4 btv = *(const float4*)&bt[u0];
    float bxa[4] = { bxv.x, bxv.y, bxv.z, bxv.w };
    float bta[4] = { btv.x, btv.y, btv.z, btv.w };

#pragma unroll
    for (int j = 0; j < 2; ++j) {
        const int grow = row0 + r_thr + 32 * j;
        const float lam = lambd[grow & (Tdim - 1)];
        float o[4];
#pragma unroll
        for (int uu = 0; uu < 4; ++uu) {
            float g  = tanhf(accx[j][uu] + bxa[uu]);
            float be = tanhf(acct[j][uu] + bta[uu]);
            o[uu] = lam * g + (1.0f - lam) * be;
        }
        *(float4*)&delta[(size_t)grow * Udim + u0] = make_float4(o[0], o[1], o[2], o[3]);
    }
}

// ---------------- Kernel 2: scores = delta @ kernel_a, softmax over T -> alpha -----------------
// Round-0 version (best measured config; every dispatch < 149 us there).
__global__ __launch_bounds__(1024, 2) void k2_softmax(
    const float* __restrict__ delta, const float* __restrict__ ka_g,
    float* __restrict__ alpha)
{
    __shared__ float dsm[2][CH * Udim];   // 2 x 16 KB
    __shared__ float ms[16][64];
    __shared__ float ls[16][64];

    const int tid = threadIdx.x;
    const int tx  = tid & 63;
    const int ty  = tid >> 6;          // 0..15
    const int b   = blockIdx.x & 31;
    const int ht  = blockIdx.x >> 5;   // 0..7
    const int h   = ht * 64 + tx;

    // kernel_a column for this lane's h (32 VGPRs)
    float ka[Udim];
#pragma unroll
    for (int u = 0; u < Udim; ++u) ka[u] = ka_g[u * Hdim + h];

    const float4* dsrc = (const float4*)(delta + (size_t)b * Tdim * Udim);

    // ---- pass 1: online (m, l) ----
    ((float4*)dsm[0])[tid] = dsrc[tid];   // stage chunk 0 (1024 float4 = 128 rows)

    float m = -1e30f, l = 0.f;
#pragma unroll 1
    for (int c = 0; c < Tdim / CH; ++c) {
        __syncthreads();
        const float* cur = dsm[c & 1];
        if (c + 1 < Tdim / CH)
            ((float4*)dsm[(c + 1) & 1])[tid] = dsrc[(size_t)(c + 1) * (CH * Udim / 4) + tid];
#pragma unroll
        for (int i = 0; i < CH / 16; ++i) {
            const int r = ty + 16 * i;
            const float4* dp = (const float4*)(cur + r * Udim);
            float4 q[8];
#pragma unroll
            for (int j = 0; j < 8; ++j) q[j] = dp[j];
            float s0 = 0.f, s1 = 0.f, s2 = 0.f, s3 = 0.f;
#pragma unroll
            for (int j = 0; j < 8; ++j) {
                s0 = fmaf(q[j].x, ka[4 * j],     s0);
                s1 = fmaf(q[j].y, ka[4 * j + 1], s1);
                s2 = fmaf(q[j].z, ka[4 * j + 2], s2);
                s3 = fmaf(q[j].w, ka[4 * j + 3], s3);
            }
            const float s = (s0 + s1) + (s2 + s3);
            const float mn = fmaxf(m, s);
            l = l * __expf(m - mn) + __expf(s - mn);
            m = mn;
        }
    }

    ms[ty][tx] = m;
    ls[ty][tx] = l;
    __syncthreads();
    float M = -1e30f;
#pragma unroll
    for (int w = 0; w < 16; ++w) M = fmaxf(M, ms[w][tx]);
    float L = 0.f;
#pragma unroll
    for (int w = 0; w < 16; ++w) L += ls[w][tx] * __expf(ms[w][tx] - M);
    const float rinv = 1.0f / L;

    // ---- pass 2: recompute scores, write alpha ----
    ((float4*)dsm[0])[tid] = dsrc[tid];   // restage chunk 0 (dsm[0] idle since c=14 sync)

    float* abase = alpha + (size_t)b * Tdim * Hdim + h;
#pragma unroll 1
    for (int c = 0; c < Tdim / CH; ++c) {
        __syncthreads();
        const float* cur = dsm[c & 1];
        if (c + 1 < Tdim / CH)
            ((float4*)dsm[(c + 1) & 1])[tid] = dsrc[(size_t)(c + 1) * (CH * Udim / 4) + tid];
#pragma unroll
        for (int i = 0; i < CH / 16; ++i) {
            const int r = ty + 16 * i;
            const int t = c * CH + r;
            const float4* dp = (const float4*)(cur + r * Udim);
            float4 q[8];
#pragma unroll
            for (int j = 0; j < 8; ++j) q[j] = dp[j];
            float s0 = 0.f, s1 = 0.f, s2 = 0.f, s3 = 0.f;
#pragma unroll
            for (int j = 0; j < 8; ++j) {
                s0 = fmaf(q[j].x, ka[4 * j],     s0);
                s1 = fmaf(q[j].y, ka[4 * j + 1], s1);
                s2 = fmaf(q[j].z, ka[4 * j + 2], s2);
                s3 = fmaf(q[j].w, ka[4 * j + 3], s3);
            }
            const float s = (s0 + s1) + (s2 + s3);
            abase[(size_t)t * Hdim] = __expf(s - M) * rinv;
        }
    }
}

extern "C" void kernel_launch(void* const* d_in, const int* in_sizes, int n_in,
                              void* d_out, int out_size, void* d_ws, size_t ws_size,
                              hipStream_t stream) {
    const float* x     = (const float*)d_in[0];
    const float* tin   = (const float*)d_in[1];
    const float* kx    = (const float*)d_in[2];
    const float* kt    = (const float*)d_in[3];
    const float* ka    = (const float*)d_in[4];
    const float* bx    = (const float*)d_in[5];
    const float* bt    = (const float*)d_in[6];
    const float* lambd = (const float*)d_in[7];
    float* alpha = (float*)d_out;
    float* delta = (float*)d_ws;   // B*T*U*4 = 8 MB

    k1_gemm_act<<<(Bdim * Tdim) / RM, 256, 0, stream>>>(x, tin, kx, kt, bx, bt, lambd, delta);
    k2_softmax<<<256, 1024, 0, stream>>>(delta, ka, alpha);
}

// Round 6
// 435.186 us; speedup vs baseline: 1.2838x; 1.1845x over previous
//
#include <hip/hip_runtime.h>
#include <cmath>

#define Hdim 512
#define Udim 32
#define Bdim 32
#define Tdim 2048
#define RM   64    // rows per block in K1 (4 waves x 16-row MFMA tiles)
#define KC   32    // k-chunk = one MFMA K
#define CH   128   // delta rows per LDS chunk in K2

typedef __attribute__((ext_vector_type(8))) short bf16x8;
typedef __attribute__((ext_vector_type(4))) float f32x4;

// round-to-nearest-even f32 -> bf16 (bits)
__device__ __forceinline__ unsigned short f2bf(float f) {
    unsigned int u = __float_as_uint(f);
    u += 0x7FFFu + ((u >> 16) & 1u);
    return (unsigned short)(u >> 16);
}
__device__ __forceinline__ float bf2f(unsigned short h) {
    return __uint_as_float(((unsigned int)h) << 16);
}

// ---------------- Kernel 1: split-bf16 MFMA GEMMs + tanh + lambd combine -> delta [B*T, U] -----
// fp32 vector GEMM had a hard LDS floor of 3 B/FMA (12 b128 per 64 FMA) ~= 123us/CU; four
// scheduling variants measured 150-251us, never below it. MFMA 16x16x32 consumes 2 b128 per
// 512 lane-FMAs. x = hi+lo bf16 split, 3 MFMAs (hh, hl, lh): residual ~2^-18 -> alpha err ~1e-8.
// LDS staged in FRAGMENT order: lane l's 8 bf16 at [tile*1024B + l*16B] -> all frag reads are
// linear conflict-free ds_read_b128. A/B frag: m(or n)=lane&15, k=8*(lane>>4)+e (contiguous-k,
// confirmed by m97/m98 arithmetic: 8 ds_read_b128 serve 16 MFMAs from k-row-major LDS);
// C/D: col=lane&15, row=(lane>>4)*4+reg (m89/m91 HW-verified).
__global__ __launch_bounds__(256, 4) void k1_gemm_act(
    const float* __restrict__ x, const float* __restrict__ tin,
    const float* __restrict__ kx, const float* __restrict__ kt,
    const float* __restrict__ bx, const float* __restrict__ bt,
    const float* __restrict__ lambd, float* __restrict__ delta)
{
    // acts: 4 tiles x 64 lanes x 8 bf16 = 2048 shorts (4 KB) per plane; weights: 2 u-tiles -> 1024
    __shared__ short axh[2048], axl[2048], ath[2048], atl[2048];   // 16 KB
    __shared__ short wxh[1024], wxl[1024], wth[1024], wtl[1024];   //  8 KB  (24 KB total)

    const int tid  = threadIdx.x;
    const int lane = tid & 63;
    const int wv   = tid >> 6;           // wave id 0..3 = row-tile
    const int row0 = blockIdx.x * RM;

    // --- act staging map: thread t loads rows (t>>3, t>>3+32), k-quad t&7 (float4) ---
    const int srow = tid >> 3;           // 0..31
    const int sk4  = tid & 7;            // float4 index in 32-k chunk
    const int aw_j0    = (sk4 & 1) * 4;        // j offset within lane's 8 bf16
    const int aw_klane = 16 * (sk4 >> 1);      // lane contribution from k-octet
    // --- weight staging map: thread t -> u = t&31, k-quad kq = t>>5 ---
    const int su  = tid & 31;
    const int skq = tid >> 5;
    const int ww_idx = (su >> 4) * 512 + ((su & 15) + 16 * (skq >> 1)) * 8 + (skq & 1) * 4;

    const float4* xg = (const float4*)x;
    const float4* tg = (const float4*)tin;

    float4 px[2], pt[2];
    float  pwx[4], pwt[4];

    f32x4 accx[2], acct_[2];
#pragma unroll
    for (int ut = 0; ut < 2; ++ut) {
        accx[ut]  = (f32x4){0.f, 0.f, 0.f, 0.f};
        acct_[ut] = (f32x4){0.f, 0.f, 0.f, 0.f};
    }

    // prefetch chunk 0
#pragma unroll
    for (int l = 0; l < 2; ++l) {
        const size_t row = (size_t)(row0 + srow + 32 * l);
        px[l] = xg[row * (Hdim / 4) + sk4];
        pt[l] = tg[row * (Hdim / 4) + sk4];
    }
#pragma unroll
    for (int i = 0; i < 4; ++i) {
        pwx[i] = kx[(size_t)(skq * 4 + i) * Udim + su];
        pwt[i] = kt[(size_t)(skq * 4 + i) * Udim + su];
    }

#pragma unroll 1
    for (int c = 0; c < Hdim / KC; ++c) {
        __syncthreads();   // previous chunk's frag readers done

        // ---- convert + write acts in fragment order ----
#pragma unroll
        for (int l = 0; l < 2; ++l) {
            const int r   = srow + 32 * l;
            const int idx = (r >> 4) * 512 + ((r & 15) + aw_klane) * 8 + aw_j0;
            float4 v = px[l];
            unsigned short h0 = f2bf(v.x), h1 = f2bf(v.y), h2 = f2bf(v.z), h3 = f2bf(v.w);
            *(short4*)&axh[idx] = make_short4((short)h0, (short)h1, (short)h2, (short)h3);
            *(short4*)&axl[idx] = make_short4(
                (short)f2bf(v.x - bf2f(h0)), (short)f2bf(v.y - bf2f(h1)),
                (short)f2bf(v.z - bf2f(h2)), (short)f2bf(v.w - bf2f(h3)));
            v = pt[l];
            h0 = f2bf(v.x); h1 = f2bf(v.y); h2 = f2bf(v.z); h3 = f2bf(v.w);
            *(short4*)&ath[idx] = make_short4((short)h0, (short)h1, (short)h2, (short)h3);
            *(short4*)&atl[idx] = make_short4(
                (short)f2bf(v.x - bf2f(h0)), (short)f2bf(v.y - bf2f(h1)),
                (short)f2bf(v.z - bf2f(h2)), (short)f2bf(v.w - bf2f(h3)));
        }
        // ---- convert + write weights in fragment order ----
        {
            unsigned short h0 = f2bf(pwx[0]), h1 = f2bf(pwx[1]), h2 = f2bf(pwx[2]), h3 = f2bf(pwx[3]);
            *(short4*)&wxh[ww_idx] = make_short4((short)h0, (short)h1, (short)h2, (short)h3);
            *(short4*)&wxl[ww_idx] = make_short4(
                (short)f2bf(pwx[0] - bf2f(h0)), (short)f2bf(pwx[1] - bf2f(h1)),
                (short)f2bf(pwx[2] - bf2f(h2)), (short)f2bf(pwx[3] - bf2f(h3)));
            h0 = f2bf(pwt[0]); h1 = f2bf(pwt[1]); h2 = f2bf(pwt[2]); h3 = f2bf(pwt[3]);
            *(short4*)&wth[ww_idx] = make_short4((short)h0, (short)h1, (short)h2, (short)h3);
            *(short4*)&wtl[ww_idx] = make_short4(
                (short)f2bf(pwt[0] - bf2f(h0)), (short)f2bf(pwt[1] - bf2f(h1)),
                (short)f2bf(pwt[2] - bf2f(h2)), (short)f2bf(pwt[3] - bf2f(h3)));
        }

        // ---- prefetch chunk c+1 ----
        if (c + 1 < Hdim / KC) {
            const int cn = c + 1;
#pragma unroll
            for (int l = 0; l < 2; ++l) {
                const size_t row = (size_t)(row0 + srow + 32 * l);
                px[l] = xg[row * (Hdim / 4) + cn * (KC / 4) + sk4];
                pt[l] = tg[row * (Hdim / 4) + cn * (KC / 4) + sk4];
            }
#pragma unroll
            for (int i = 0; i < 4; ++i) {
                pwx[i] = kx[(size_t)(cn * KC + skq * 4 + i) * Udim + su];
                pwt[i] = kt[(size_t)(cn * KC + skq * 4 + i) * Udim + su];
            }
        }

        __syncthreads();   // staged writes visible

        // ---- frag reads (linear, conflict-free) + 12 MFMA ----
        const int ab = wv * 512 + lane * 8;
        bf16x8 Axh = *(const bf16x8*)&axh[ab];
        bf16x8 Axl = *(const bf16x8*)&axl[ab];
        bf16x8 Ath = *(const bf16x8*)&ath[ab];
        bf16x8 Atl = *(const bf16x8*)&atl[ab];
#pragma unroll
        for (int ut = 0; ut < 2; ++ut) {
            const int wb = ut * 512 + lane * 8;
            bf16x8 Bh = *(const bf16x8*)&wxh[wb];
            bf16x8 Bl = *(const bf16x8*)&wxl[wb];
            accx[ut] = __builtin_amdgcn_mfma_f32_16x16x32_bf16(Axh, Bh, accx[ut], 0, 0, 0);
            accx[ut] = __builtin_amdgcn_mfma_f32_16x16x32_bf16(Axh, Bl, accx[ut], 0, 0, 0);
            accx[ut] = __builtin_amdgcn_mfma_f32_16x16x32_bf16(Axl, Bh, accx[ut], 0, 0, 0);
            Bh = *(const bf16x8*)&wth[wb];
            Bl = *(const bf16x8*)&wtl[wb];
            acct_[ut] = __builtin_amdgcn_mfma_f32_16x16x32_bf16(Ath, Bh, acct_[ut], 0, 0, 0);
            acct_[ut] = __builtin_amdgcn_mfma_f32_16x16x32_bf16(Ath, Bl, acct_[ut], 0, 0, 0);
            acct_[ut] = __builtin_amdgcn_mfma_f32_16x16x32_bf16(Atl, Bh, acct_[ut], 0, 0, 0);
        }
    }

    // ---- epilogue: C/D layout col=lane&15, row=(lane>>4)*4+reg ----
    const int crow = (lane >> 4) * 4;
    const int ccol = lane & 15;
    const float bx0 = bx[ccol],      bt0 = bt[ccol];
    const float bx1 = bx[16 + ccol], bt1 = bt[16 + ccol];
#pragma unroll
    for (int r = 0; r < 4; ++r) {
        const int grow = row0 + wv * 16 + crow + r;
        const float lam = lambd[grow & (Tdim - 1)];
        float g0  = tanhf(accx[0][r] + bx0);
        float be0 = tanhf(acct_[0][r] + bt0);
        float g1  = tanhf(accx[1][r] + bx1);
        float be1 = tanhf(acct_[1][r] + bt1);
        delta[(size_t)grow * Udim + ccol]      = lam * g0 + (1.0f - lam) * be0;
        delta[(size_t)grow * Udim + 16 + ccol] = lam * g1 + (1.0f - lam) * be1;
    }
}

// ---------------- Kernel 2: scores = delta @ kernel_a, softmax over T -> alpha -----------------
// Round-0 version (best measured config).
__global__ __launch_bounds__(1024, 2) void k2_softmax(
    const float* __restrict__ delta, const float* __restrict__ ka_g,
    float* __restrict__ alpha)
{
    __shared__ float dsm[2][CH * Udim];   // 2 x 16 KB
    __shared__ float ms[16][64];
    __shared__ float ls[16][64];

    const int tid = threadIdx.x;
    const int tx  = tid & 63;
    const int ty  = tid >> 6;          // 0..15
    const int b   = blockIdx.x & 31;
    const int ht  = blockIdx.x >> 5;   // 0..7
    const int h   = ht * 64 + tx;

    float ka[Udim];
#pragma unroll
    for (int u = 0; u < Udim; ++u) ka[u] = ka_g[u * Hdim + h];

    const float4* dsrc = (const float4*)(delta + (size_t)b * Tdim * Udim);

    // ---- pass 1: online (m, l) ----
    ((float4*)dsm[0])[tid] = dsrc[tid];

    float m = -1e30f, l = 0.f;
#pragma unroll 1
    for (int c = 0; c < Tdim / CH; ++c) {
        __syncthreads();
        const float* cur = dsm[c & 1];
        if (c + 1 < Tdim / CH)
            ((float4*)dsm[(c + 1) & 1])[tid] = dsrc[(size_t)(c + 1) * (CH * Udim / 4) + tid];
#pragma unroll
        for (int i = 0; i < CH / 16; ++i) {
            const int r = ty + 16 * i;
            const float4* dp = (const float4*)(cur + r * Udim);
            float4 q[8];
#pragma unroll
            for (int j = 0; j < 8; ++j) q[j] = dp[j];
            float s0 = 0.f, s1 = 0.f, s2 = 0.f, s3 = 0.f;
#pragma unroll
            for (int j = 0; j < 8; ++j) {
                s0 = fmaf(q[j].x, ka[4 * j],     s0);
                s1 = fmaf(q[j].y, ka[4 * j + 1], s1);
                s2 = fmaf(q[j].z, ka[4 * j + 2], s2);
                s3 = fmaf(q[j].w, ka[4 * j + 3], s3);
            }
            const float s = (s0 + s1) + (s2 + s3);
            const float mn = fmaxf(m, s);
            l = l * __expf(m - mn) + __expf(s - mn);
            m = mn;
        }
    }

    ms[ty][tx] = m;
    ls[ty][tx] = l;
    __syncthreads();
    float M = -1e30f;
#pragma unroll
    for (int w = 0; w < 16; ++w) M = fmaxf(M, ms[w][tx]);
    float L = 0.f;
#pragma unroll
    for (int w = 0; w < 16; ++w) L += ls[w][tx] * __expf(ms[w][tx] - M);
    const float rinv = 1.0f / L;

    // ---- pass 2: recompute scores, write alpha ----
    ((float4*)dsm[0])[tid] = dsrc[tid];

    float* abase = alpha + (size_t)b * Tdim * Hdim + h;
#pragma unroll 1
    for (int c = 0; c < Tdim / CH; ++c) {
        __syncthreads();
        const float* cur = dsm[c & 1];
        if (c + 1 < Tdim / CH)
            ((float4*)dsm[(c + 1) & 1])[tid] = dsrc[(size_t)(c + 1) * (CH * Udim / 4) + tid];
#pragma unroll
        for (int i = 0; i < CH / 16; ++i) {
            const int r = ty + 16 * i;
            const int t = c * CH + r;
            const float4* dp = (const float4*)(cur + r * Udim);
            float4 q[8];
#pragma unroll
            for (int j = 0; j < 8; ++j) q[j] = dp[j];
            float s0 = 0.f, s1 = 0.f, s2 = 0.f, s3 = 0.f;
#pragma unroll
            for (int j = 0; j < 8; ++j) {
                s0 = fmaf(q[j].x, ka[4 * j],     s0);
                s1 = fmaf(q[j].y, ka[4 * j + 1], s1);
                s2 = fmaf(q[j].z, ka[4 * j + 2], s2);
                s3 = fmaf(q[j].w, ka[4 * j + 3], s3);
            }
            const float s = (s0 + s1) + (s2 + s3);
            abase[(size_t)t * Hdim] = __expf(s - M) * rinv;
        }
    }
}

extern "C" void kernel_launch(void* const* d_in, const int* in_sizes, int n_in,
                              void* d_out, int out_size, void* d_ws, size_t ws_size,
                              hipStream_t stream) {
    const float* x     = (const float*)d_in[0];
    const float* tin   = (const float*)d_in[1];
    const float* kx    = (const float*)d_in[2];
    const float* kt    = (const float*)d_in[3];
    const float* ka    = (const float*)d_in[4];
    const float* bx    = (const float*)d_in[5];
    const float* bt    = (const float*)d_in[6];
    const float* lambd = (const float*)d_in[7];
    float* alpha = (float*)d_out;
    float* delta = (float*)d_ws;   // B*T*U*4 = 8 MB

    k1_gemm_act<<<(Bdim * Tdim) / RM, 256, 0, stream>>>(x, tin, kx, kt, bx, bt, lambd, delta);
    k2_softmax<<<256, 1024, 0, stream>>>(delta, ka, alpha);
}